// Round 10
// baseline (43.279 us; speedup 1.0000x reference)
//
#include <hip/hip_runtime.h>
#include <stdint.h>
#include <cmath>

#define NVARS   1024
#define NEDGES  3072
#define BATCHSZ 2048
#define RPT     16
#define HALF    8
#define ROWSTR  (BATCHSZ/RPT)   /* 128 */
#define LOG2E   1.4426950408889634f

// Single-instruction rotate on device.
__host__ __device__ __forceinline__ uint32_t rotl32(uint32_t x, int r) {
#if defined(__HIP_DEVICE_COMPILE__)
    return __builtin_amdgcn_alignbit(x, x, (uint32_t)(32 - r));
#else
    return (x << r) | (x >> (32 - r));
#endif
}

// Host threefry for key derivation (jax.random.split of key(42)).
__host__ __forceinline__ void threefry2x32_host(uint32_t k0, uint32_t k1,
                                                uint32_t x0, uint32_t x1,
                                                uint32_t& o0, uint32_t& o1) {
    uint32_t k2 = k0 ^ k1 ^ 0x1BD11BDAu;
    const int rots[20] = {13,15,26,6, 17,29,16,24, 13,15,26,6, 17,29,16,24, 13,15,26,6};
    x0 += k0; x1 += k1;
    int rc = 0;
    const uint32_t ka[5] = {k1, k2, k0, k1, k2};
    const uint32_t kb[5] = {k2, k0, k1, k2, k0};
    for (int g = 0; g < 5; g++) {
        for (int i = 0; i < 4; i++) {
            x0 += x1; x1 = rotl32(x1, rots[rc++]); x1 ^= x0;
        }
        x0 += ka[g]; x1 += kb[g] + (uint32_t)(g + 1);
    }
    o0 = x0; o1 = x1;
}

// Four independent threefry chains, instruction-interleaved, with the
// key-injection merged into the next round's x0-add (v_add3_u32).
__device__ __forceinline__ void threefry_quad_xor(
        uint32_t k0, uint32_t k1,
        uint32_t i0, uint32_t i1, uint32_t i2, uint32_t i3,
        uint32_t& m0, uint32_t& m1, uint32_t& m2, uint32_t& m3) {
    uint32_t k2 = k0 ^ k1 ^ 0x1BD11BDAu;
    uint32_t a0 = k0, a1 = i0 + k1;
    uint32_t b0 = k0, b1 = i1 + k1;
    uint32_t c0 = k0, c1 = i2 + k1;
    uint32_t d0 = k0, d1 = i3 + k1;
#define ROT4(r) \
    a1 = rotl32(a1, r); b1 = rotl32(b1, r); c1 = rotl32(c1, r); d1 = rotl32(d1, r); \
    a1 ^= a0; b1 ^= b0; c1 ^= c0; d1 ^= d0;
#define R4(r) \
    a0 += a1; b0 += b1; c0 += c1; d0 += d1; \
    ROT4(r)
#define IR4(ka, kb, r) \
    a1 += (kb); b1 += (kb); c1 += (kb); d1 += (kb); \
    a0 = a0 + (ka) + a1; b0 = b0 + (ka) + b1; \
    c0 = c0 + (ka) + c1; d0 = d0 + (ka) + d1; \
    ROT4(r)
    R4(13) R4(15) R4(26) R4(6)
    IR4(k1, k2 + 1u, 17) R4(29) R4(16) R4(24)
    IR4(k2, k0 + 2u, 13) R4(15) R4(26) R4(6)
    IR4(k0, k1 + 3u, 17) R4(29) R4(16) R4(24)
    IR4(k1, k2 + 4u, 13) R4(15) R4(26) R4(6)
#undef R4
#undef IR4
#undef ROT4
    m0 = (a0 + k2) ^ (a1 + k0 + 5u);
    m1 = (b0 + k2) ^ (b1 + k0 + 5u);
    m2 = (c0 + k2) ^ (c1 + k0 + 5u);
    m3 = (d0 + k2) ^ (d1 + k0 + 5u);
}

// tanh(0.5*o) with o pre-scaled by log2e: tanh = 1 - 2/(1 + 2^o2).
__device__ __forceinline__ float tanh_half_2(float o2) {
    float ex = __builtin_amdgcn_exp2f(o2);
    return 1.0f - 2.0f * __builtin_amdgcn_rcpf(ex + 1.0f);
}

#define ISTEP ((uint32_t)ROWSTR * NEDGES)        /* 393216 elements  */
#define XSTEP (ISTEP * 4u)                       /* 1572864 bytes    */
#define LSTEP ((uint32_t)ROWSTR * NVARS * 4u)    /* 524288 bytes     */

// Fully fused, RPT=16 in two 8-row halves: per-edge setup (sibling indices
// are pure arithmetic from edge_var = repeat(arange(1024),3); the f64
// sigmoid -> T9 threshold is computed ONCE per thread, amortized over 16
// outputs) + dropout-count + tanh epilogue. Grid = 1536 blocks -> all
// co-resident (single residency batch).
__global__ __launch_bounds__(256, 6) void
odd_layer_fused(const float* __restrict__ x, const float* __restrict__ llr,
                const float* __restrict__ oddw, const float* __restrict__ llrw,
                const float* __restrict__ logits, const int* __restrict__ echk,
                float* __restrict__ out,
                uint32_t k0a, uint32_t k1a, uint32_t k0b, uint32_t k1b,
                uint32_t k0c, uint32_t k1c) {
    const int e  = blockIdx.x * 256 + threadIdx.x;   // 0..3071
    const int b0 = blockIdx.y;                       // 0..127

    // Sibling edges from structure: e = 3*v + r3; siblings are the other
    // two edges of the group (distinct checks by construction).
    const int v    = e / 3;
    const int r3   = e - v * 3;
    const int base = v * 3;
    const int o1 = base + ((r3 + 1) == 3 ? 0 : r3 + 1);
    const int o2 = base + (r3 == 0 ? 2 : r3 - 1);

    // Per-edge setup loads (no dependent hop; land under threefry wall).
    const float w1r = oddw[(size_t)o1 * NEDGES + e];
    const float w2r = oddw[(size_t)o2 * NEDGES + e];
    const float vwr = llrw[(size_t)v * NEDGES + e];
    const float lg  = logits[e];
    const int   ce  = echk[e];
    const int   c1  = echk[o1];
    const int   c2  = echk[o2];

    // Double-precision sigmoid -> exact integer threshold (bit-identical to
    // the R1-R9 proven path): u < kp  <=>  bits < ceil(kp*2^23)<<9.
    const float kpf = (float)(1.0 / (1.0 + exp(-(double)lg)));
    const double Td = ceil((double)kpf * 8388608.0);
    const uint32_t T9 = (Td >= 8388608.0) ? 0xFFFFFFFFu : (((uint32_t)Td) << 9);
    const float w1 = (c1 != ce) ? w1r * LOG2E : 0.0f;
    const float w2 = (c2 != ce) ? w2r * LOG2E : 0.0f;
    const float vw = vwr * LOG2E;

    // Wave-uniform byte bases (SGPR); per-access offsets are 32-bit VGPRs.
    const char* xb = (const char*)(x   + (size_t)b0 * NEDGES);
    const char* lb = (const char*)(llr + (size_t)b0 * NVARS);
    char*       ob = (char*)      (out + (size_t)b0 * NEDGES);

    const uint32_t sx4 = (uint32_t)o1 << 2;
    const uint32_t sy4 = (uint32_t)o2 << 2;
    const uint32_t sz4 = (uint32_t)v << 2;
    const uint32_t i0  = (uint32_t)b0 * NEDGES + (uint32_t)e;
    const uint32_t e4  = (uint32_t)e << 2;

#pragma unroll
    for (int h = 0; h < 2; ++h) {
        const uint32_t rb = (uint32_t)h * HALF;      // row offset of this half

        // Issue this half's 24 gathers; consumed only in the epilogue.
        float xv1[HALF], xv2[HALF], lvv[HALF];
#pragma unroll
        for (int r = 0; r < HALF; r++) {
            const uint32_t rr = rb + r;
            xv1[r] = *(const float*)(xb + (sx4 + rr * XSTEP));
            xv2[r] = *(const float*)(xb + (sy4 + rr * XSTEP));
            lvv[r] = *(const float*)(lb + (sz4 + rr * LSTEP));
        }

        // 24 threefry chains (3 members x 8 rows), quad-interleaved.
        uint32_t m[3][HALF];
#pragma unroll
        for (int j = 0; j < 3; j++) {
            const uint32_t kk0 = (j == 0) ? k0a : (j == 1) ? k0b : k0c;
            const uint32_t kk1 = (j == 0) ? k1a : (j == 1) ? k1b : k1c;
            const uint32_t ib = i0 + rb * ISTEP;
            threefry_quad_xor(kk0, kk1,
                              ib,              ib + ISTEP,
                              ib + 2u * ISTEP, ib + 3u * ISTEP,
                              m[j][0], m[j][1], m[j][2], m[j][3]);
            threefry_quad_xor(kk0, kk1,
                              ib + 4u * ISTEP, ib + 5u * ISTEP,
                              ib + 6u * ISTEP, ib + 7u * ISTEP,
                              m[j][4], m[j][5], m[j][6], m[j][7]);
        }

#pragma unroll
        for (int r = 0; r < HALF; r++) {
            const uint32_t rr = rb + r;
            const int cnt = ((m[0][r] < T9) ? 1 : 0) + ((m[1][r] < T9) ? 1 : 0)
                          + ((m[2][r] < T9) ? 1 : 0);
            float xa = fmaf(xv2[r], w2, xv1[r] * w1);   // log2e-scaled
            float t0 = tanh_half_2(xa);
            float t1 = tanh_half_2(fmaf(lvv[r], vw, xa));
            float res = fmaf((float)cnt, (t1 - t0) * (1.0f / 3.0f), t0);
            // Non-temporal: don't let the output stream evict x from L2.
            __builtin_nontemporal_store(res, (float*)(ob + (e4 + rr * XSTEP)));
        }
    }
}

extern "C" void kernel_launch(void* const* d_in, const int* in_sizes, int n_in,
                              void* d_out, int out_size, void* d_ws, size_t ws_size,
                              hipStream_t stream) {
    const float* x      = (const float*)d_in[0];
    const float* llr    = (const float*)d_in[1];
    const float* oddw   = (const float*)d_in[2];
    const float* llrw   = (const float*)d_in[3];
    const float* logits = (const float*)d_in[4];
    const int*   echk   = (const int*)d_in[6];
    float* out = (float*)d_out;

    // jax.random.split(jax.random.key(42), 3), partitionable scheme.
    uint32_t k0[3], k1[3];
    for (uint32_t j = 0; j < 3; j++) {
        threefry2x32_host(0u, 42u, 0u, j, k0[j], k1[j]);
    }

    dim3 grid(NEDGES / 256, ROWSTR);
    odd_layer_fused<<<grid, 256, 0, stream>>>(x, llr, oddw, llrw, logits, echk,
                                              out,
                                              k0[0], k1[0], k0[1], k1[1],
                                              k0[2], k1[2]);
}

// Round 11
// 42.430 us; speedup vs baseline: 1.0200x; 1.0200x over previous
//
#include <hip/hip_runtime.h>
#include <stdint.h>
#include <cmath>

#define NVARS   1024
#define NEDGES  3072
#define BATCHSZ 2048
#define RPT     8
#define ROWSTR  (BATCHSZ/RPT)   /* 256 */
#define LOG2E   1.4426950408889634f

// Single-instruction rotate on device.
__host__ __device__ __forceinline__ uint32_t rotl32(uint32_t x, int r) {
#if defined(__HIP_DEVICE_COMPILE__)
    return __builtin_amdgcn_alignbit(x, x, (uint32_t)(32 - r));
#else
    return (x << r) | (x >> (32 - r));
#endif
}

// Host threefry for key derivation (jax.random.split of key(42)).
__host__ __forceinline__ void threefry2x32_host(uint32_t k0, uint32_t k1,
                                                uint32_t x0, uint32_t x1,
                                                uint32_t& o0, uint32_t& o1) {
    uint32_t k2 = k0 ^ k1 ^ 0x1BD11BDAu;
    const int rots[20] = {13,15,26,6, 17,29,16,24, 13,15,26,6, 17,29,16,24, 13,15,26,6};
    x0 += k0; x1 += k1;
    int rc = 0;
    const uint32_t ka[5] = {k1, k2, k0, k1, k2};
    const uint32_t kb[5] = {k2, k0, k1, k2, k0};
    for (int g = 0; g < 5; g++) {
        for (int i = 0; i < 4; i++) {
            x0 += x1; x1 = rotl32(x1, rots[rc++]); x1 ^= x0;
        }
        x0 += ka[g]; x1 += kb[g] + (uint32_t)(g + 1);
    }
    o0 = x0; o1 = x1;
}

// Four independent threefry chains, instruction-interleaved, with the
// key-injection merged into the next round's x0-add (v_add3_u32).
__device__ __forceinline__ void threefry_quad_xor(
        uint32_t k0, uint32_t k1,
        uint32_t i0, uint32_t i1, uint32_t i2, uint32_t i3,
        uint32_t& m0, uint32_t& m1, uint32_t& m2, uint32_t& m3) {
    uint32_t k2 = k0 ^ k1 ^ 0x1BD11BDAu;
    uint32_t a0 = k0, a1 = i0 + k1;
    uint32_t b0 = k0, b1 = i1 + k1;
    uint32_t c0 = k0, c1 = i2 + k1;
    uint32_t d0 = k0, d1 = i3 + k1;
#define ROT4(r) \
    a1 = rotl32(a1, r); b1 = rotl32(b1, r); c1 = rotl32(c1, r); d1 = rotl32(d1, r); \
    a1 ^= a0; b1 ^= b0; c1 ^= c0; d1 ^= d0;
#define R4(r) \
    a0 += a1; b0 += b1; c0 += c1; d0 += d1; \
    ROT4(r)
#define IR4(ka, kb, r) \
    a1 += (kb); b1 += (kb); c1 += (kb); d1 += (kb); \
    a0 = a0 + (ka) + a1; b0 = b0 + (ka) + b1; \
    c0 = c0 + (ka) + c1; d0 = d0 + (ka) + d1; \
    ROT4(r)
    R4(13) R4(15) R4(26) R4(6)
    IR4(k1, k2 + 1u, 17) R4(29) R4(16) R4(24)
    IR4(k2, k0 + 2u, 13) R4(15) R4(26) R4(6)
    IR4(k0, k1 + 3u, 17) R4(29) R4(16) R4(24)
    IR4(k1, k2 + 4u, 13) R4(15) R4(26) R4(6)
#undef R4
#undef IR4
#undef ROT4
    m0 = (a0 + k2) ^ (a1 + k0 + 5u);
    m1 = (b0 + k2) ^ (b1 + k0 + 5u);
    m2 = (c0 + k2) ^ (c1 + k0 + 5u);
    m3 = (d0 + k2) ^ (d1 + k0 + 5u);
}

// tanh(0.5*o) with o pre-scaled by log2e: tanh = 1 - 2/(1 + 2^o2).
__device__ __forceinline__ float tanh_half_2(float o2) {
    float ex = __builtin_amdgcn_exp2f(o2);
    return 1.0f - 2.0f * __builtin_amdgcn_rcpf(ex + 1.0f);
}

#define ISTEP ((uint32_t)ROWSTR * NEDGES)        /* 786432 elements   */
#define XSTEP (ISTEP * 4u)                       /* 3145728 bytes     */
#define LSTEP ((uint32_t)ROWSTR * NVARS * 4u)    /* 1048576 bytes     */

// Fully fused (best-measured config, R9): per-edge setup (sibling indices
// are pure arithmetic from edge_var = repeat(arange(1024),3); weights +
// f64-sigmoid threshold ride under the threefry wall) + dropout-count +
// tanh epilogue. One dispatch. RPT=8/3072 blocks beat RPT=16/1536 (R10:
// occupancy collapsed 56->35%) and the split setup-kernel (R8: +4.1us
// dispatch overhead on the bench).
__global__ __launch_bounds__(256, 8) void
odd_layer_fused(const float* __restrict__ x, const float* __restrict__ llr,
                const float* __restrict__ oddw, const float* __restrict__ llrw,
                const float* __restrict__ logits, const int* __restrict__ echk,
                float* __restrict__ out,
                uint32_t k0a, uint32_t k1a, uint32_t k0b, uint32_t k1b,
                uint32_t k0c, uint32_t k1c) {
    const int e  = blockIdx.x * 256 + threadIdx.x;   // 0..3071
    const int b0 = blockIdx.y;                       // 0..255

    // Sibling edges from structure: e = 3*v + r3, siblings are the other
    // two edges of the group (distinct checks by construction).
    const int v    = e / 3;
    const int r3   = e - v * 3;
    const int base = v * 3;
    const int o1 = base + ((r3 + 1) == 3 ? 0 : r3 + 1);
    const int o2 = base + (r3 == 0 ? 2 : r3 - 1);

    // Issue per-edge setup loads immediately (no dependent hop).
    const float w1r = oddw[(size_t)o1 * NEDGES + e];
    const float w2r = oddw[(size_t)o2 * NEDGES + e];
    const float vwr = llrw[(size_t)v * NEDGES + e];
    const float lg  = logits[e];
    const int   ce  = echk[e];
    const int   c1  = echk[o1];
    const int   c2  = echk[o2];

    // Wave-uniform byte bases (SGPR); per-access offsets are 32-bit VGPRs.
    const char* xb = (const char*)(x   + (size_t)b0 * NEDGES);
    const char* lb = (const char*)(llr + (size_t)b0 * NVARS);
    char*       ob = (char*)      (out + (size_t)b0 * NEDGES);

    // Issue all 24 gathers now; consumed only in the epilogue.
    const uint32_t sx4 = (uint32_t)o1 << 2;
    const uint32_t sy4 = (uint32_t)o2 << 2;
    const uint32_t sz4 = (uint32_t)v << 2;
    float xv1[RPT], xv2[RPT], lvv[RPT];
#pragma unroll
    for (int r = 0; r < RPT; r++) {
        xv1[r] = *(const float*)(xb + (sx4 + r * XSTEP));
        xv2[r] = *(const float*)(xb + (sy4 + r * XSTEP));
        lvv[r] = *(const float*)(lb + (sz4 + r * LSTEP));
    }

    const uint32_t i0 = (uint32_t)b0 * NEDGES + (uint32_t)e;

    // 24 threefry chains (3 members x 8 rows), quad-interleaved.
    uint32_t m[3][RPT];
#pragma unroll
    for (int j = 0; j < 3; j++) {
        const uint32_t kk0 = (j == 0) ? k0a : (j == 1) ? k0b : k0c;
        const uint32_t kk1 = (j == 0) ? k1a : (j == 1) ? k1b : k1c;
        threefry_quad_xor(kk0, kk1, i0,              i0 + ISTEP,
                                     i0 + 2u * ISTEP, i0 + 3u * ISTEP,
                          m[j][0], m[j][1], m[j][2], m[j][3]);
        threefry_quad_xor(kk0, kk1, i0 + 4u * ISTEP, i0 + 5u * ISTEP,
                                     i0 + 6u * ISTEP, i0 + 7u * ISTEP,
                          m[j][4], m[j][5], m[j][6], m[j][7]);
    }

    // Per-edge setup math (loads long since landed, hidden under threefry).
    // Double-precision sigmoid -> exact integer threshold, bit-identical to
    // the proven R1-R9 setup path:  u < kp  <=>  bits < ceil(kp*2^23)<<9.
    const float kpf = (float)(1.0 / (1.0 + exp(-(double)lg)));
    const double Td = ceil((double)kpf * 8388608.0);
    const uint32_t T9 = (Td >= 8388608.0) ? 0xFFFFFFFFu : (((uint32_t)Td) << 9);
    const float w1 = (c1 != ce) ? w1r * LOG2E : 0.0f;
    const float w2 = (c2 != ce) ? w2r * LOG2E : 0.0f;
    const float vw = vwr * LOG2E;

    const uint32_t e4 = (uint32_t)e << 2;
#pragma unroll
    for (int r = 0; r < RPT; r++) {
        const int cnt = ((m[0][r] < T9) ? 1 : 0) + ((m[1][r] < T9) ? 1 : 0)
                      + ((m[2][r] < T9) ? 1 : 0);
        float xa = fmaf(xv2[r], w2, xv1[r] * w1);       // log2e-scaled
        float t0 = tanh_half_2(xa);
        float t1 = tanh_half_2(fmaf(lvv[r], vw, xa));
        float res = fmaf((float)cnt, (t1 - t0) * (1.0f / 3.0f), t0);
        // Non-temporal: don't let the 24MB output stream evict x from L2.
        __builtin_nontemporal_store(res, (float*)(ob + (e4 + r * XSTEP)));
    }
}

extern "C" void kernel_launch(void* const* d_in, const int* in_sizes, int n_in,
                              void* d_out, int out_size, void* d_ws, size_t ws_size,
                              hipStream_t stream) {
    const float* x      = (const float*)d_in[0];
    const float* llr    = (const float*)d_in[1];
    const float* oddw   = (const float*)d_in[2];
    const float* llrw   = (const float*)d_in[3];
    const float* logits = (const float*)d_in[4];
    const int*   echk   = (const int*)d_in[6];
    float* out = (float*)d_out;

    // jax.random.split(jax.random.key(42), 3), partitionable scheme.
    uint32_t k0[3], k1[3];
    for (uint32_t j = 0; j < 3; j++) {
        threefry2x32_host(0u, 42u, 0u, j, k0[j], k1[j]);
    }

    dim3 grid(NEDGES / 256, ROWSTR);
    odd_layer_fused<<<grid, 256, 0, stream>>>(x, llr, oddw, llrw, logits, echk,
                                              out,
                                              k0[0], k1[0], k0[1], k1[1],
                                              k0[2], k1[2]);
}